// Round 8
// baseline (152.784 us; speedup 1.0000x reference)
//
#include <hip/hip_runtime.h>
#include <stdint.h>

#define NB 4
#define NC 17
#define HH 8
#define SS 512
#define DD 64

typedef __attribute__((ext_vector_type(8))) short bf16x8;
typedef __attribute__((ext_vector_type(4))) float f32x4;

// ws layout (bytes):
//   W1mbf : [17][8][64][64] bf16 = 1,114,112
//   Tg    : [64 bh][5 P][512 j][64 m] bf16 = 20,971,520
#define WS_W1 0
#define WS_T  1114112

__device__ __forceinline__ unsigned short f2bf(float f) {
  unsigned int x; __builtin_memcpy(&x, &f, 4);
  return (unsigned short)((x + 0x7fff + ((x >> 16) & 1)) >> 16);
}
__device__ __forceinline__ bf16x8 cvt8(float4 a, float4 b) {
  union { bf16x8 v; unsigned short u[8]; } t;
  t.u[0] = f2bf(a.x); t.u[1] = f2bf(a.y); t.u[2] = f2bf(a.z); t.u[3] = f2bf(a.w);
  t.u[4] = f2bf(b.x); t.u[5] = f2bf(b.y); t.u[6] = f2bf(b.z); t.u[7] = f2bf(b.w);
  return t.v;
}

// ---- K0: W1mbf[c][h][.] = sum_B W1[B][h][.] * softmax(alpha, axis=B)[c,B,h] ----
__global__ __launch_bounds__(256) void k_prep(const float* __restrict__ W1,
                                              const float* __restrict__ alpha,
                                              unsigned short* __restrict__ W1mbf) {
  int tid = threadIdx.x;
  int c = blockIdx.x >> 3, hh = blockIdx.x & 7;
  __shared__ float sm[NB];
  if (tid == 0) {
    float a[NB], mx = -1e30f;
    for (int B = 0; B < NB; B++) { a[B] = alpha[(c * NB + B) * HH + hh]; mx = fmaxf(mx, a[B]); }
    float s = 0.f;
    for (int B = 0; B < NB; B++) { a[B] = __expf(a[B] - mx); s += a[B]; }
    for (int B = 0; B < NB; B++) sm[B] = a[B] / s;
  }
  __syncthreads();
  float s0 = sm[0], s1 = sm[1], s2 = sm[2], s3 = sm[3];
  for (int idx = tid; idx < DD * DD; idx += blockDim.x) {
    float v = W1[((0 * HH + hh) * DD * DD) + idx] * s0 +
              W1[((1 * HH + hh) * DD * DD) + idx] * s1 +
              W1[((2 * HH + hh) * DD * DD) + idx] * s2 +
              W1[((3 * HH + hh) * DD * DD) + idx] * s3;
    W1mbf[((size_t)(c * HH + hh)) * DD * DD + idx] = f2bf(v);
  }
}

// ---- K1: build Tg[bh][P][j][m] (bf16, natural j) per (bh, 64-col tile).
// Grouped MFMA compute into LDS, then LINEAR dump to global.
__global__ __launch_bounds__(256) void k_T(const float* __restrict__ key,
                                           const int* __restrict__ bseq,
                                           const unsigned short* __restrict__ W1mbf,
                                           unsigned short* __restrict__ Tg) {
  int bx = blockIdx.x;
  int bh = bx & 63, jt = bx >> 6;     // same-bh blocks share an XCD
  int b = bh >> 3, h = bh & 7;
  int j0 = jt * 64;
  int tid = threadIdx.x, wave = tid >> 6, lane = tid & 63;
  int quad = lane >> 4, l16 = lane & 15;

  __shared__ __align__(16) unsigned short Tl[5][64][72];  // 46,080 B
  __shared__ int ord[64], lgs[6], cnt[5], cur[5];
  __shared__ int p1list[44], n1s[5], n1b[5], n1tot;

  if (tid < 5) cnt[tid] = 0;
  __syncthreads();
  int mybj = 0;
  if (tid < 64) { mybj = bseq[b * SS + j0 + tid]; atomicAdd(&cnt[mybj], 1); }
  __syncthreads();
  if (tid == 0) {
    lgs[0] = 0;
    for (int a = 0; a < 5; a++) lgs[a + 1] = lgs[a] + cnt[a];
  }
  __syncthreads();
  if (tid < 5) cur[tid] = lgs[tid];
  __syncthreads();
  if (tid < 64) ord[atomicAdd(&cur[mybj], 1)] = tid;
  if (tid < 5) n1s[tid] = ((lgs[tid + 1] - lgs[tid] + 15) >> 4) * ((tid == 0) ? 1 : 5);
  __syncthreads();
  if (tid == 0) {
    int a0 = 0;
    for (int a = 0; a < 5; a++) { n1b[a] = a0; a0 += n1s[a]; }
    n1tot = a0;
  }
  __syncthreads();
  if (tid < 5) {
    int a = tid;
    int ls = lgs[a], le = lgs[a + 1];
    int w = n1b[a];
    for (int t0 = ls; t0 < le; t0 += 16) {
      if (a == 0) {
        p1list[w++] = t0 | (le << 6) | (1 << 21);  // c=0, bcast to all planes
      } else {
        for (int B = 0; B < 5; B++) {
          int c = (B == 0) ? 0 : (B - 1) * NB + a;
          p1list[w++] = t0 | (le << 6) | (c << 13) | (B << 18);
        }
      }
    }
  }
  __syncthreads();

  for (int idx = wave; idx < n1tot; idx += 4) {
    int e = p1list[idx];
    int t0 = e & 63, le = (e >> 6) & 127, c = (e >> 13) & 31, B = (e >> 18) & 7;
    int bc = (e >> 21) & 1;
    const unsigned short* Wc = W1mbf + ((size_t)(c * HH + h) << 12);
    int p = t0 + l16; if (p > le - 1) p = le - 1;
    int cl = ord[p];
    const float* kp = &key[((size_t)(bh * SS + j0 + cl)) * DD + quad * 8];
    float4 ka = *(const float4*)kp, kb = *(const float4*)(kp + 4);
    float4 kc = *(const float4*)(kp + 32), kd = *(const float4*)(kp + 36);
    bf16x8 af0 = cvt8(ka, kb);
    bf16x8 af1 = cvt8(kc, kd);
    int cr[4];
#pragma unroll
    for (int reg = 0; reg < 4; reg++) {
      int pr = t0 + quad * 4 + reg;
      cr[reg] = (pr < le) ? ord[pr] : -1;
    }
#pragma unroll
    for (int nt = 0; nt < 4; nt++) {
      const unsigned short* wp = &Wc[(nt * 16 + l16) * DD + quad * 8];
      bf16x8 b0 = *(const bf16x8*)wp;
      bf16x8 b1 = *(const bf16x8*)(wp + 32);
      f32x4 acc = {0.f, 0.f, 0.f, 0.f};
      acc = __builtin_amdgcn_mfma_f32_16x16x32_bf16(af0, b0, acc, 0, 0, 0);
      acc = __builtin_amdgcn_mfma_f32_16x16x32_bf16(af1, b1, acc, 0, 0, 0);
#pragma unroll
      for (int reg = 0; reg < 4; reg++) {
        if (cr[reg] >= 0) {
          unsigned short v = f2bf(acc[reg]);
          if (bc) {
#pragma unroll
            for (int Bw = 0; Bw < 5; Bw++) Tl[Bw][cr[reg]][nt * 16 + l16] = v;
          } else {
            Tl[B][cr[reg]][nt * 16 + l16] = v;
          }
        }
      }
    }
  }
  __syncthreads();

  // linear dump: 5*64*64 bf16 = 40,960 B, coalesced dwordx4
  unsigned short* dst = Tg + (size_t)bh * 5 * SS * DD;
#pragma unroll
  for (int it = 0; it < 10; it++) {
    int selem = it * 2048 + tid * 8;        // short index
    int plane = selem >> 12;
    int rem = selem & 4095;
    int col = rem >> 6, m = rem & 63;
    uint4 v = *(const uint4*)&Tl[plane][col][m];
    *(uint4*)&dst[((size_t)(plane * SS + j0 + col)) * DD + m] = v;
  }
}

// ---- K2: block = (bh, 32-row slab). Dense natural-order GEMM vs Tg, 5-plane
// select per row, accumulate in LDS, then ONE linear 128 KB store stream.
__global__ __launch_bounds__(256) void k_scores(const float* __restrict__ query,
                                                const int* __restrict__ bseq,
                                                const unsigned short* __restrict__ Tg,
                                                float* __restrict__ out) {
  int bx = blockIdx.x;
  int bh = bx & 63, slab = bx >> 6;
  int b = bh >> 3;
  int i0 = slab * 32;
  int tid = threadIdx.x, wave = tid >> 6, lane = tid & 63;
  int quad = lane >> 4, l16 = lane & 15;
#define ROWP 516
  __shared__ __align__(16) float Ost[32][ROWP];  // 66,048 B

  const unsigned short* Tp = Tg + (size_t)bh * 5 * SS * DD;

  // A-fragments + row buckets for both 16-row tiles
  bf16x8 af[2][2];
  int Bq[2][4];
#pragma unroll
  for (int rt = 0; rt < 2; rt++) {
    int p0 = i0 + rt * 16;
    const float* qp = &query[((size_t)(bh * SS + p0 + l16)) * DD + quad * 8];
    float4 a0 = *(const float4*)qp, a1 = *(const float4*)(qp + 4);
    float4 a2 = *(const float4*)(qp + 32), a3 = *(const float4*)(qp + 36);
    af[rt][0] = cvt8(a0, a1);
    af[rt][1] = cvt8(a2, a3);
#pragma unroll
    for (int reg = 0; reg < 4; reg++)
      Bq[rt][reg] = bseq[b * SS + p0 + quad * 4 + reg];
  }

  for (int ct = wave; ct < 32; ct += 4) {
    int j0 = ct * 16;
    bf16x8 bf0[5], bf1[5];
#pragma unroll
    for (int P = 0; P < 5; P++) {
      const unsigned short* tp = &Tp[((size_t)(P * SS + j0 + l16)) * DD + quad * 8];
      bf0[P] = *(const bf16x8*)tp;
      bf1[P] = *(const bf16x8*)(tp + 32);
    }
#pragma unroll
    for (int rt = 0; rt < 2; rt++) {
      f32x4 acc[5];
#pragma unroll
      for (int P = 0; P < 5; P++) {
        f32x4 z = {0.f, 0.f, 0.f, 0.f};
        z = __builtin_amdgcn_mfma_f32_16x16x32_bf16(af[rt][0], bf0[P], z, 0, 0, 0);
        z = __builtin_amdgcn_mfma_f32_16x16x32_bf16(af[rt][1], bf1[P], z, 0, 0, 0);
        acc[P] = z;
      }
#pragma unroll
      for (int reg = 0; reg < 4; reg++) {
        int Bv = Bq[rt][reg];
        float v = acc[0][reg];
        v = (Bv == 1) ? acc[1][reg] : v;
        v = (Bv == 2) ? acc[2][reg] : v;
        v = (Bv == 3) ? acc[3][reg] : v;
        v = (Bv == 4) ? acc[4][reg] : v;
        Ost[rt * 16 + quad * 4 + reg][j0 + l16] = v;
      }
    }
  }
  __syncthreads();

  // linear store: one contiguous 32*512*4 = 128 KB slab per block
  size_t base = ((size_t)(bh * SS + i0)) * SS;
#pragma unroll
  for (int it = 0; it < 16; it++) {
    int elem = it * 1024 + tid * 4;
    int r = elem >> 9, cc = elem & 511;
    float4 v = *(const float4*)&Ost[r][cc];
    *(float4*)&out[base + elem] = v;
  }
#undef ROWP
}

extern "C" void kernel_launch(void* const* d_in, const int* in_sizes, int n_in,
                              void* d_out, int out_size, void* d_ws, size_t ws_size,
                              hipStream_t stream) {
  const float* q = (const float*)d_in[0];
  const float* k = (const float*)d_in[1];
  const int* bseq = (const int*)d_in[2];
  const float* W1 = (const float*)d_in[3];
  const float* alpha = (const float*)d_in[4];
  float* out = (float*)d_out;
  char* ws = (char*)d_ws;
  unsigned short* W1mbf = (unsigned short*)(ws + WS_W1);
  unsigned short* Tg = (unsigned short*)(ws + WS_T);

  hipLaunchKernelGGL(k_prep, dim3(NC * HH), dim3(256), 0, stream, W1, alpha, W1mbf);
  hipLaunchKernelGGL(k_T, dim3(64 * (SS / 64)), dim3(256), 0, stream,
                     k, bseq, W1mbf, Tg);
  hipLaunchKernelGGL(k_scores, dim3(64 * (SS / 32)), dim3(256), 0, stream,
                     q, bseq, Tg, out);
}